// Round 5
// baseline (253.310 us; speedup 1.0000x reference)
//
#include <hip/hip_runtime.h>

// cumprod(1 - betas) over N = 33,554,432 fp32 elements.
// betas = linspace(1e-4, 0.02): the running product underflows to exactly
// +0.0f after ~6e5 elements, so ~98% of the output is exact zeros. k_final
// exploits this: when a block's carry-in prefix is 0.0f, it skips the betas
// re-read and streams zeros (block-uniform branch, bit-exact vs reference).
//
// 3-phase scan:
//   k_block_prod : product of each 1024-elem chunk -> bp[bid]   (read 128 MiB)
//   k_scan_bp    : one block: exclusive prefix products of bp    (tiny)
//   k_final      : carry-in==0 -> stream zeros (no input read);
//                  else recompute local prefixes * carry-in      (~2 MiB read,
//                                                                 128 MiB write)
// All global accesses coalesced 16B; output stores non-temporal (nt) so the
// write stream doesn't evict anything useful from L3. No divisions.

typedef float f32x4 __attribute__((ext_vector_type(4)));  // native vector for nt stores

#define BLOCK 256
#define EPB   (BLOCK * 4)   // 1024 elements per block
#define SEQ   32            // k_scan_bp: block products per thread (max 32768 blocks)

__global__ __launch_bounds__(BLOCK) void k_block_prod(const float* __restrict__ betas,
                                                      float* __restrict__ bp, int n) {
    const int tid  = threadIdx.x;
    const int bid  = blockIdx.x;
    const long i4  = ((long)bid * BLOCK + tid) * 4;

    float a[4] = {1.0f, 1.0f, 1.0f, 1.0f};
    if (i4 + 4 <= n) {
        f32x4 b = *reinterpret_cast<const f32x4*>(betas + i4);
        a[0] = 1.0f - b.x; a[1] = 1.0f - b.y; a[2] = 1.0f - b.z; a[3] = 1.0f - b.w;
    } else {
#pragma unroll
        for (int k = 0; k < 4; ++k) {
            long i = i4 + k;
            if (i < n) a[k] = 1.0f - betas[i];
        }
    }
    float t = (a[0] * a[1]) * (a[2] * a[3]);

    // wave64 product reduce
#pragma unroll
    for (int off = 1; off < 64; off <<= 1) t *= __shfl_xor(t, off, 64);

    __shared__ float w[BLOCK / 64];
    const int lane = tid & 63, wid = tid >> 6;
    if (lane == 0) w[wid] = t;
    __syncthreads();
    if (tid == 0) bp[bid] = (w[0] * w[1]) * (w[2] * w[3]);
}

__global__ __launch_bounds__(1024) void k_scan_bp(const float* __restrict__ bp,
                                                  float* __restrict__ excl, int nb) {
    const int tid  = threadIdx.x;
    const int base = tid * SEQ;
    const int lane = tid & 63, wid = tid >> 6;

    float v[SEQ];
    float t = 1.0f;
#pragma unroll
    for (int k = 0; k < SEQ; ++k) {
        float x = (base + k < nb) ? bp[base + k] : 1.0f;
        v[k] = x;
        t *= x;
    }

    // wave64 inclusive scan of per-thread totals
    float incl = t;
#pragma unroll
    for (int off = 1; off < 64; off <<= 1) {
        float u = __shfl_up(incl, off, 64);
        if (lane >= off) incl *= u;
    }

    __shared__ float wtot[1024 / 64];
    if (lane == 63) wtot[wid] = incl;
    __syncthreads();

    float wexcl = 1.0f;
    for (int q = 0; q < wid; ++q) wexcl *= wtot[q];

    float texcl = __shfl_up(incl, 1, 64);
    if (lane == 0) texcl = 1.0f;

    float run = wexcl * texcl;   // exclusive prefix of this thread's chunk
#pragma unroll
    for (int k = 0; k < SEQ; ++k) {
        if (base + k < nb) excl[base + k] = run;
        run *= v[k];
    }
}

__global__ __launch_bounds__(BLOCK) void k_final(const float* __restrict__ betas,
                                                 const float* __restrict__ excl,
                                                 float* __restrict__ out, int n) {
    const int tid = threadIdx.x;
    const int bid = blockIdx.x;
    const long i4 = ((long)bid * BLOCK + tid) * 4;
    const bool full = (i4 + 4 <= n);

    __shared__ float s_carry;
    if (tid == 0) s_carry = excl[bid];
    __syncthreads();
    const float carry = s_carry;

    // Underflow fast path: carry-in is exactly +0.0 -> every output of this
    // block is exactly +0.0 (all alphas finite positive). Skip the input read.
    if (carry == 0.0f) {
        if (full) {
            f32x4 z = {0.0f, 0.0f, 0.0f, 0.0f};
            __builtin_nontemporal_store(z, reinterpret_cast<f32x4*>(out + i4));
        } else {
            for (int k = 0; k < 4; ++k) {
                long i = i4 + k;
                if (i < n) out[i] = 0.0f;
            }
        }
        return;
    }

    float a[4] = {1.0f, 1.0f, 1.0f, 1.0f};
    if (full) {
        f32x4 b = *reinterpret_cast<const f32x4*>(betas + i4);
        a[0] = 1.0f - b.x; a[1] = 1.0f - b.y; a[2] = 1.0f - b.z; a[3] = 1.0f - b.w;
    } else {
#pragma unroll
        for (int k = 0; k < 4; ++k) {
            long i = i4 + k;
            if (i < n) a[k] = 1.0f - betas[i];
        }
    }

    // per-thread running (inclusive) products
    float r0 = a[0];
    float r1 = r0 * a[1];
    float r2 = r1 * a[2];
    float r3 = r2 * a[3];

    // wave64 inclusive scan of thread totals
    const int lane = tid & 63, wid = tid >> 6;
    float incl = r3;
#pragma unroll
    for (int off = 1; off < 64; off <<= 1) {
        float u = __shfl_up(incl, off, 64);
        if (lane >= off) incl *= u;
    }

    __shared__ float wtot[BLOCK / 64];
    if (lane == 63) wtot[wid] = incl;
    __syncthreads();

    float wexcl = 1.0f;
#pragma unroll
    for (int q = 0; q < BLOCK / 64; ++q)
        if (q < wid) wexcl *= wtot[q];

    float texcl = __shfl_up(incl, 1, 64);
    if (lane == 0) texcl = 1.0f;

    const float p = carry * wexcl * texcl;   // exclusive prefix of this thread

    if (full) {
        f32x4 o;
        o.x = p * r0; o.y = p * r1; o.z = p * r2; o.w = p * r3;
        __builtin_nontemporal_store(o, reinterpret_cast<f32x4*>(out + i4));
    } else {
#pragma unroll
        for (int k = 0; k < 4; ++k) {
            long i = i4 + k;
            if (i < n) {
                float r = (k == 0) ? r0 : (k == 1) ? r1 : (k == 2) ? r2 : r3;
                out[i] = p * r;
            }
        }
    }
}

extern "C" void kernel_launch(void* const* d_in, const int* in_sizes, int n_in,
                              void* d_out, int out_size, void* d_ws, size_t ws_size,
                              hipStream_t stream) {
    const float* betas = (const float*)d_in[0];
    float* out = (float*)d_out;
    const int n  = in_sizes[0];
    const int nb = (n + EPB - 1) / EPB;   // 32768 for n = 2^25 (max supported: 32768)

    float* bp   = (float*)d_ws;
    float* excl = bp + nb;

    k_block_prod<<<nb, BLOCK, 0, stream>>>(betas, bp, n);
    k_scan_bp<<<1, 1024, 0, stream>>>(bp, excl, nb);
    k_final<<<nb, BLOCK, 0, stream>>>(betas, excl, out, n);
}

// Round 8
// 206.729 us; speedup vs baseline: 1.2253x; 1.2253x over previous
//
#include <hip/hip_runtime.h>

// cumprod(1 - betas), N = 2^25 fp32. The running fp32 product underflows to
// exactly +0.0 at element ~5.6e5 (tile ~547). Structure (all data-driven, no
// input assumptions):
//   k1 head_bp   : block products for tiles [0, HEAD)            (read 8.4 MB)
//   k2 head_scan : scan head; excl[0..HEAD); if inclusive(HEAD-1)==0 ->
//                  zflag=1, zero-fill excl[HEAD..nb)              (tiny)
//   k3 tail_bp   : fallback only: if zflag -> exit; else bp for tail tiles
//   k4 tail_scan : fallback only: if zflag -> exit; else scan tail
//   k5 final     : carry==0 -> nt-stream zeros (no read);
//                  else recompute local prefixes * carry          (~2.2 MB read,
//                                                                  134 MB write)
// Zero-skip is sound: once the computed carry is exactly +0.0, every later
// output is exactly +0.0 (0 * finite = 0); tail bp values are then irrelevant.
// On non-linspace inputs the k3/k4 fallback computes the full general scan.

typedef float f32x4 __attribute__((ext_vector_type(4)));

#define BLOCK 256
#define EPB   1024      // elements per tile (BLOCK * 4)
#define HEAD  2048      // head tiles scanned eagerly (covers 2.1M elements)
#define SEQ_H 2         // HEAD / 1024
#define SEQ_T 30        // (32768 - HEAD) / 1024

// ---------------- k1: head block products ----------------
__global__ __launch_bounds__(BLOCK) void k1_head_bp(const float* __restrict__ betas,
                                                    float* __restrict__ bp, int n) {
    const int tid = threadIdx.x;
    const int bid = blockIdx.x;                 // tile id (< HEAD)
    const long i4 = ((long)bid * BLOCK + tid) * 4;

    float a[4] = {1.0f, 1.0f, 1.0f, 1.0f};
    if (i4 + 4 <= n) {
        f32x4 b = *reinterpret_cast<const f32x4*>(betas + i4);
        a[0] = 1.0f - b.x; a[1] = 1.0f - b.y; a[2] = 1.0f - b.z; a[3] = 1.0f - b.w;
    } else {
#pragma unroll
        for (int k = 0; k < 4; ++k) { long i = i4 + k; if (i < n) a[k] = 1.0f - betas[i]; }
    }
    float t = (a[0] * a[1]) * (a[2] * a[3]);
#pragma unroll
    for (int off = 1; off < 64; off <<= 1) t *= __shfl_xor(t, off, 64);

    __shared__ float w[BLOCK / 64];
    const int lane = tid & 63, wid = tid >> 6;
    if (lane == 0) w[wid] = t;
    __syncthreads();
    if (tid == 0) bp[bid] = (w[0] * w[1]) * (w[2] * w[3]);
}

// ---------------- k2: head scan + zero detection ----------------
__global__ __launch_bounds__(1024) void k2_head_scan(const float* __restrict__ bp,
                                                     float* __restrict__ excl,
                                                     int* __restrict__ zflag, int nb) {
    const int tid  = threadIdx.x;
    const int base = tid * SEQ_H;
    const int lane = tid & 63, wid = tid >> 6;
    const int hb   = (nb < HEAD) ? nb : HEAD;   // valid head tiles

    float v[SEQ_H];
    float t = 1.0f;
#pragma unroll
    for (int k = 0; k < SEQ_H; ++k) {
        float x = (base + k < hb) ? bp[base + k] : 1.0f;
        v[k] = x; t *= x;
    }

    float incl = t;
#pragma unroll
    for (int off = 1; off < 64; off <<= 1) {
        float u = __shfl_up(incl, off, 64);
        if (lane >= off) incl *= u;
    }

    __shared__ float wtot[1024 / 64];
    if (lane == 63) wtot[wid] = incl;
    __syncthreads();

    float wexcl = 1.0f;
#pragma unroll
    for (int q = 0; q < 1024 / 64; ++q) if (q < wid) wexcl *= wtot[q];

    float texcl = __shfl_up(incl, 1, 64);
    if (lane == 0) texcl = 1.0f;

    float run = wexcl * texcl;
#pragma unroll
    for (int k = 0; k < SEQ_H; ++k) {
        if (base + k < hb) excl[base + k] = run;
        run *= v[k];
    }

    // thread 1023's final run == inclusive product of all valid head tiles
    __shared__ int s_zf;
    if (tid == 1023) {
        int zf = (run == 0.0f) ? 1 : 0;
        s_zf = zf;
        *zflag = zf;
    }
    __syncthreads();

    // zero carry confirmed within head -> all later excl are exactly 0
    if (s_zf) {
        for (int j = HEAD + tid; j < nb; j += 1024) excl[j] = 0.0f;
    }
}

// ---------------- k3: tail block products (fallback only) ----------------
__global__ __launch_bounds__(BLOCK) void k3_tail_bp(const float* __restrict__ betas,
                                                    float* __restrict__ bp,
                                                    const int* __restrict__ zflag,
                                                    int n, int nb) {
    __shared__ int s_zf;
    if (threadIdx.x == 0) s_zf = *zflag;
    __syncthreads();
    if (s_zf) return;                           // zero-carry path: tail bp unused

    const int tid = threadIdx.x;
    const int lane = tid & 63, wid = tid >> 6;
    __shared__ float w[BLOCK / 64];

    for (int tile = HEAD + blockIdx.x; tile < nb; tile += gridDim.x) {
        const long i4 = ((long)tile * EPB) + (long)tid * 4;
        float a[4] = {1.0f, 1.0f, 1.0f, 1.0f};
        if (i4 + 4 <= n) {
            f32x4 b = *reinterpret_cast<const f32x4*>(betas + i4);
            a[0] = 1.0f - b.x; a[1] = 1.0f - b.y; a[2] = 1.0f - b.z; a[3] = 1.0f - b.w;
        } else {
#pragma unroll
            for (int k = 0; k < 4; ++k) { long i = i4 + k; if (i < n) a[k] = 1.0f - betas[i]; }
        }
        float t = (a[0] * a[1]) * (a[2] * a[3]);
#pragma unroll
        for (int off = 1; off < 64; off <<= 1) t *= __shfl_xor(t, off, 64);
        if (lane == 0) w[wid] = t;
        __syncthreads();
        if (tid == 0) bp[tile] = (w[0] * w[1]) * (w[2] * w[3]);
        __syncthreads();
    }
}

// ---------------- k4: tail scan (fallback only) ----------------
__global__ __launch_bounds__(1024) void k4_tail_scan(const float* __restrict__ bp,
                                                     float* __restrict__ excl,
                                                     const int* __restrict__ zflag, int nb) {
    if (*zflag) return;
    if (nb <= HEAD) return;

    const int tid  = threadIdx.x;
    const int base = HEAD + tid * SEQ_T;
    const int lane = tid & 63, wid = tid >> 6;

    const float seed = excl[HEAD - 1] * bp[HEAD - 1];   // inclusive through head

    float v[SEQ_T];
    float t = 1.0f;
#pragma unroll
    for (int k = 0; k < SEQ_T; ++k) {
        float x = (base + k < nb) ? bp[base + k] : 1.0f;
        v[k] = x; t *= x;
    }

    float incl = t;
#pragma unroll
    for (int off = 1; off < 64; off <<= 1) {
        float u = __shfl_up(incl, off, 64);
        if (lane >= off) incl *= u;
    }

    __shared__ float wtot[1024 / 64];
    if (lane == 63) wtot[wid] = incl;
    __syncthreads();

    float wexcl = 1.0f;
#pragma unroll
    for (int q = 0; q < 1024 / 64; ++q) if (q < wid) wexcl *= wtot[q];

    float texcl = __shfl_up(incl, 1, 64);
    if (lane == 0) texcl = 1.0f;

    float run = seed * wexcl * texcl;
#pragma unroll
    for (int k = 0; k < SEQ_T; ++k) {
        if (base + k < nb) excl[base + k] = run;
        run *= v[k];
    }
}

// ---------------- k5: final output ----------------
__global__ __launch_bounds__(BLOCK) void k5_final(const float* __restrict__ betas,
                                                  const float* __restrict__ excl,
                                                  float* __restrict__ out, int n) {
    const int tid = threadIdx.x;
    const int bid = blockIdx.x;
    const long i4 = ((long)bid * BLOCK + tid) * 4;
    const bool full = (i4 + 4 <= n);

    __shared__ float s_carry;
    if (tid == 0) s_carry = excl[bid];
    __syncthreads();
    const float carry = s_carry;

    if (carry == 0.0f) {                         // exact-zero region: no read
        if (full) {
            f32x4 z = {0.0f, 0.0f, 0.0f, 0.0f};
            __builtin_nontemporal_store(z, reinterpret_cast<f32x4*>(out + i4));
        } else {
            for (int k = 0; k < 4; ++k) { long i = i4 + k; if (i < n) out[i] = 0.0f; }
        }
        return;
    }

    float a[4] = {1.0f, 1.0f, 1.0f, 1.0f};
    if (full) {
        f32x4 b = *reinterpret_cast<const f32x4*>(betas + i4);
        a[0] = 1.0f - b.x; a[1] = 1.0f - b.y; a[2] = 1.0f - b.z; a[3] = 1.0f - b.w;
    } else {
#pragma unroll
        for (int k = 0; k < 4; ++k) { long i = i4 + k; if (i < n) a[k] = 1.0f - betas[i]; }
    }

    float r0 = a[0];
    float r1 = r0 * a[1];
    float r2 = r1 * a[2];
    float r3 = r2 * a[3];

    const int lane = tid & 63, wid = tid >> 6;
    float incl = r3;
#pragma unroll
    for (int off = 1; off < 64; off <<= 1) {
        float u = __shfl_up(incl, off, 64);
        if (lane >= off) incl *= u;
    }

    __shared__ float wtot[BLOCK / 64];
    if (lane == 63) wtot[wid] = incl;
    __syncthreads();

    float wexcl = 1.0f;
#pragma unroll
    for (int q = 0; q < BLOCK / 64; ++q) if (q < wid) wexcl *= wtot[q];

    float texcl = __shfl_up(incl, 1, 64);
    if (lane == 0) texcl = 1.0f;

    const float p = carry * wexcl * texcl;

    if (full) {
        f32x4 o;
        o.x = p * r0; o.y = p * r1; o.z = p * r2; o.w = p * r3;
        __builtin_nontemporal_store(o, reinterpret_cast<f32x4*>(out + i4));
    } else {
#pragma unroll
        for (int k = 0; k < 4; ++k) {
            long i = i4 + k;
            if (i < n) {
                float r = (k == 0) ? r0 : (k == 1) ? r1 : (k == 2) ? r2 : r3;
                out[i] = p * r;
            }
        }
    }
}

extern "C" void kernel_launch(void* const* d_in, const int* in_sizes, int n_in,
                              void* d_out, int out_size, void* d_ws, size_t ws_size,
                              hipStream_t stream) {
    const float* betas = (const float*)d_in[0];
    float* out = (float*)d_out;
    const int n  = in_sizes[0];
    const int nb = (n + EPB - 1) / EPB;          // 32768 for n = 2^25

    float* bp    = (float*)d_ws;                 // [0, nb)
    float* excl  = bp + nb;                      // [nb, 2nb)
    int*   zflag = (int*)(excl + nb);            // 1 int

    const int g1 = (nb < HEAD) ? nb : HEAD;

    k1_head_bp  <<<g1,   BLOCK, 0, stream>>>(betas, bp, n);
    k2_head_scan<<<1,    1024,  0, stream>>>(bp, excl, zflag, nb);
    k3_tail_bp  <<<2048, BLOCK, 0, stream>>>(betas, bp, zflag, n, nb);
    k4_tail_scan<<<1,    1024,  0, stream>>>(bp, excl, zflag, nb);
    k5_final    <<<nb,   BLOCK, 0, stream>>>(betas, excl, out, n);
}

// Round 14
// 204.956 us; speedup vs baseline: 1.2359x; 1.0087x over previous
//
#include <hip/hip_runtime.h>

// cumprod(1 - betas), N = 2^25 fp32. The running fp32 product underflows to
// exactly +0.0 at element ~4.5e5 (tile ~440-550). Structure (data-driven, no
// input assumptions):
//   k1 head_bp   : block products for tiles [0, HEAD)            (read 4.2 MB)
//   k2 head_scan : scan head; excl[0..HEAD); if inclusive(HEAD-1)==0 ->
//                  zflag=1, zero-fill excl[HEAD..nb)              (tiny)
//   k3 tail_bp   : fallback only: if zflag -> exit; else bp for tail tiles
//   k4 tail_scan : fallback only: if zflag -> exit; else scan tail
//   k5 final     : carry==0 -> nt-stream zeros (no read);
//                  else recompute local prefixes * carry          (~1.8 MB read,
//                                                                  134 MB write)
// Zero-skip is sound: once the computed carry is exactly +0.0, every later
// output is exactly +0.0 (0 * finite = 0); tail bp values are then irrelevant.
// On non-linspace inputs the k3/k4 fallback computes the full general scan.

typedef float f32x4 __attribute__((ext_vector_type(4)));

#define BLOCK 256
#define EPB   1024      // elements per tile (BLOCK * 4)
#define HEAD  1024      // head tiles scanned eagerly (covers 1.05M elements)
#define SEQ_H 1         // HEAD / 1024
#define SEQ_T 31        // (32768 - HEAD) / 1024

// ---------------- k1: head block products ----------------
__global__ __launch_bounds__(BLOCK) void k1_head_bp(const float* __restrict__ betas,
                                                    float* __restrict__ bp, int n) {
    const int tid = threadIdx.x;
    const int bid = blockIdx.x;                 // tile id (< HEAD)
    const long i4 = ((long)bid * BLOCK + tid) * 4;

    float a[4] = {1.0f, 1.0f, 1.0f, 1.0f};
    if (i4 + 4 <= n) {
        f32x4 b = *reinterpret_cast<const f32x4*>(betas + i4);
        a[0] = 1.0f - b.x; a[1] = 1.0f - b.y; a[2] = 1.0f - b.z; a[3] = 1.0f - b.w;
    } else {
#pragma unroll
        for (int k = 0; k < 4; ++k) { long i = i4 + k; if (i < n) a[k] = 1.0f - betas[i]; }
    }
    float t = (a[0] * a[1]) * (a[2] * a[3]);
#pragma unroll
    for (int off = 1; off < 64; off <<= 1) t *= __shfl_xor(t, off, 64);

    __shared__ float w[BLOCK / 64];
    const int lane = tid & 63, wid = tid >> 6;
    if (lane == 0) w[wid] = t;
    __syncthreads();
    if (tid == 0) bp[bid] = (w[0] * w[1]) * (w[2] * w[3]);
}

// ---------------- k2: head scan + zero detection ----------------
__global__ __launch_bounds__(1024) void k2_head_scan(const float* __restrict__ bp,
                                                     float* __restrict__ excl,
                                                     int* __restrict__ zflag, int nb) {
    const int tid  = threadIdx.x;
    const int base = tid * SEQ_H;
    const int lane = tid & 63, wid = tid >> 6;
    const int hb   = (nb < HEAD) ? nb : HEAD;   // valid head tiles

    float v[SEQ_H];
    float t = 1.0f;
#pragma unroll
    for (int k = 0; k < SEQ_H; ++k) {
        float x = (base + k < hb) ? bp[base + k] : 1.0f;
        v[k] = x; t *= x;
    }

    float incl = t;
#pragma unroll
    for (int off = 1; off < 64; off <<= 1) {
        float u = __shfl_up(incl, off, 64);
        if (lane >= off) incl *= u;
    }

    __shared__ float wtot[1024 / 64];
    if (lane == 63) wtot[wid] = incl;
    __syncthreads();

    float wexcl = 1.0f;
#pragma unroll
    for (int q = 0; q < 1024 / 64; ++q) if (q < wid) wexcl *= wtot[q];

    float texcl = __shfl_up(incl, 1, 64);
    if (lane == 0) texcl = 1.0f;

    float run = wexcl * texcl;
#pragma unroll
    for (int k = 0; k < SEQ_H; ++k) {
        if (base + k < hb) excl[base + k] = run;
        run *= v[k];
    }

    // thread 1023's final run == inclusive product of all valid head tiles
    __shared__ int s_zf;
    if (tid == 1023) {
        int zf = (run == 0.0f) ? 1 : 0;
        s_zf = zf;
        *zflag = zf;
    }
    __syncthreads();

    // zero carry confirmed within head -> all later excl are exactly 0
    if (s_zf) {
        for (int j = HEAD + tid; j < nb; j += 1024) excl[j] = 0.0f;
    }
}

// ---------------- k3: tail block products (fallback only) ----------------
__global__ __launch_bounds__(BLOCK) void k3_tail_bp(const float* __restrict__ betas,
                                                    float* __restrict__ bp,
                                                    const int* __restrict__ zflag,
                                                    int n, int nb) {
    __shared__ int s_zf;
    if (threadIdx.x == 0) s_zf = *zflag;
    __syncthreads();
    if (s_zf) return;                           // zero-carry path: tail bp unused

    const int tid = threadIdx.x;
    const int lane = tid & 63, wid = tid >> 6;
    __shared__ float w[BLOCK / 64];

    for (int tile = HEAD + blockIdx.x; tile < nb; tile += gridDim.x) {
        const long i4 = ((long)tile * EPB) + (long)tid * 4;
        float a[4] = {1.0f, 1.0f, 1.0f, 1.0f};
        if (i4 + 4 <= n) {
            f32x4 b = *reinterpret_cast<const f32x4*>(betas + i4);
            a[0] = 1.0f - b.x; a[1] = 1.0f - b.y; a[2] = 1.0f - b.z; a[3] = 1.0f - b.w;
        } else {
#pragma unroll
            for (int k = 0; k < 4; ++k) { long i = i4 + k; if (i < n) a[k] = 1.0f - betas[i]; }
        }
        float t = (a[0] * a[1]) * (a[2] * a[3]);
#pragma unroll
        for (int off = 1; off < 64; off <<= 1) t *= __shfl_xor(t, off, 64);
        if (lane == 0) w[wid] = t;
        __syncthreads();
        if (tid == 0) bp[tile] = (w[0] * w[1]) * (w[2] * w[3]);
        __syncthreads();
    }
}

// ---------------- k4: tail scan (fallback only) ----------------
__global__ __launch_bounds__(1024) void k4_tail_scan(const float* __restrict__ bp,
                                                     float* __restrict__ excl,
                                                     const int* __restrict__ zflag, int nb) {
    if (*zflag) return;
    if (nb <= HEAD) return;

    const int tid  = threadIdx.x;
    const int base = HEAD + tid * SEQ_T;
    const int lane = tid & 63, wid = tid >> 6;

    const float seed = excl[HEAD - 1] * bp[HEAD - 1];   // inclusive through head

    float v[SEQ_T];
    float t = 1.0f;
#pragma unroll
    for (int k = 0; k < SEQ_T; ++k) {
        float x = (base + k < nb) ? bp[base + k] : 1.0f;
        v[k] = x; t *= x;
    }

    float incl = t;
#pragma unroll
    for (int off = 1; off < 64; off <<= 1) {
        float u = __shfl_up(incl, off, 64);
        if (lane >= off) incl *= u;
    }

    __shared__ float wtot[1024 / 64];
    if (lane == 63) wtot[wid] = incl;
    __syncthreads();

    float wexcl = 1.0f;
#pragma unroll
    for (int q = 0; q < 1024 / 64; ++q) if (q < wid) wexcl *= wtot[q];

    float texcl = __shfl_up(incl, 1, 64);
    if (lane == 0) texcl = 1.0f;

    float run = seed * wexcl * texcl;
#pragma unroll
    for (int k = 0; k < SEQ_T; ++k) {
        if (base + k < nb) excl[base + k] = run;
        run *= v[k];
    }
}

// ---------------- k5: final output ----------------
__global__ __launch_bounds__(BLOCK) void k5_final(const float* __restrict__ betas,
                                                  const float* __restrict__ excl,
                                                  float* __restrict__ out, int n) {
    const int tid = threadIdx.x;
    const int bid = blockIdx.x;
    const long i4 = ((long)bid * BLOCK + tid) * 4;
    const bool full = (i4 + 4 <= n);

    __shared__ float s_carry;
    if (tid == 0) s_carry = excl[bid];
    __syncthreads();
    const float carry = s_carry;

    if (carry == 0.0f) {                         // exact-zero region: no read
        if (full) {
            f32x4 z = {0.0f, 0.0f, 0.0f, 0.0f};
            __builtin_nontemporal_store(z, reinterpret_cast<f32x4*>(out + i4));
        } else {
            for (int k = 0; k < 4; ++k) { long i = i4 + k; if (i < n) out[i] = 0.0f; }
        }
        return;
    }

    float a[4] = {1.0f, 1.0f, 1.0f, 1.0f};
    if (full) {
        f32x4 b = *reinterpret_cast<const f32x4*>(betas + i4);
        a[0] = 1.0f - b.x; a[1] = 1.0f - b.y; a[2] = 1.0f - b.z; a[3] = 1.0f - b.w;
    } else {
#pragma unroll
        for (int k = 0; k < 4; ++k) { long i = i4 + k; if (i < n) a[k] = 1.0f - betas[i]; }
    }

    float r0 = a[0];
    float r1 = r0 * a[1];
    float r2 = r1 * a[2];
    float r3 = r2 * a[3];

    const int lane = tid & 63, wid = tid >> 6;
    float incl = r3;
#pragma unroll
    for (int off = 1; off < 64; off <<= 1) {
        float u = __shfl_up(incl, off, 64);
        if (lane >= off) incl *= u;
    }

    __shared__ float wtot[BLOCK / 64];
    if (lane == 63) wtot[wid] = incl;
    __syncthreads();

    float wexcl = 1.0f;
#pragma unroll
    for (int q = 0; q < BLOCK / 64; ++q) if (q < wid) wexcl *= wtot[q];

    float texcl = __shfl_up(incl, 1, 64);
    if (lane == 0) texcl = 1.0f;

    const float p = carry * wexcl * texcl;

    if (full) {
        f32x4 o;
        o.x = p * r0; o.y = p * r1; o.z = p * r2; o.w = p * r3;
        __builtin_nontemporal_store(o, reinterpret_cast<f32x4*>(out + i4));
    } else {
#pragma unroll
        for (int k = 0; k < 4; ++k) {
            long i = i4 + k;
            if (i < n) {
                float r = (k == 0) ? r0 : (k == 1) ? r1 : (k == 2) ? r2 : r3;
                out[i] = p * r;
            }
        }
    }
}

extern "C" void kernel_launch(void* const* d_in, const int* in_sizes, int n_in,
                              void* d_out, int out_size, void* d_ws, size_t ws_size,
                              hipStream_t stream) {
    const float* betas = (const float*)d_in[0];
    float* out = (float*)d_out;
    const int n  = in_sizes[0];
    const int nb = (n + EPB - 1) / EPB;          // 32768 for n = 2^25

    float* bp    = (float*)d_ws;                 // [0, nb)
    float* excl  = bp + nb;                      // [nb, 2nb)
    int*   zflag = (int*)(excl + nb);            // 1 int

    const int g1 = (nb < HEAD) ? nb : HEAD;

    k1_head_bp  <<<g1,   BLOCK, 0, stream>>>(betas, bp, n);
    k2_head_scan<<<1,    1024,  0, stream>>>(bp, excl, zflag, nb);
    k3_tail_bp  <<<1024, BLOCK, 0, stream>>>(betas, bp, zflag, n, nb);
    k4_tail_scan<<<1,    1024,  0, stream>>>(bp, excl, zflag, nb);
    k5_final    <<<nb,   BLOCK, 0, stream>>>(betas, excl, out, n);
}